// Round 2
// baseline (600.777 us; speedup 1.0000x reference)
//
#include <hip/hip_runtime.h>
#include <math.h>

typedef __bf16 bf16_t;
typedef __attribute__((ext_vector_type(8))) __bf16 bf16x8;
typedef __attribute__((ext_vector_type(4))) __bf16 bf16x4;
typedef __attribute__((ext_vector_type(4))) float f32x4;

#define AS_GLOBAL __attribute__((address_space(1)))
#define AS_LDS    __attribute__((address_space(3)))

__device__ __forceinline__ void async_copy16(const bf16_t* g, bf16_t* l) {
  __builtin_amdgcn_global_load_lds((const AS_GLOBAL void*)g, (AS_LDS void*)l, 16, 0, 0);
}

// fp32 -> bf16 cast, 4 elements/thread
__global__ __launch_bounds__(256) void cast_f32_bf16(
    const float* __restrict__ in, bf16_t* __restrict__ out, int n) {
  int i = (blockIdx.x * blockDim.x + threadIdx.x) * 4;
  if (i >= n) return;
  float4 v = *(const float4*)(in + i);
  bf16x4 o;
  o[0] = (bf16_t)v.x; o[1] = (bf16_t)v.y; o[2] = (bf16_t)v.z; o[3] = (bf16_t)v.w;
  *(bf16x4*)(out + i) = o;
}

// C[M x Ncols] = A[M x K] @ B[Ncols x K]^T   (A,B bf16 row-major)
// 128x128 tile, BK=64, 256 threads (4 waves), mfma 16x16x32 bf16.
// LDS staged via global_load_lds(16B); XOR swizzle (16B seg at phys ks^(row&7))
// keeps ds_read_b128 conflict-free while satisfying the wave-uniform-base
// constraint of global_load_lds (lds addr == base + lane*16).
// MODE 0: bf16 C[row*ldc+col] = acc*scale + bias[col]
// MODE 1: bf16 C[col*ldc+row] = acc + bias[col]              (transposed store)
// MODE 2: f32  C[row*ldc+col] = acc + bias[col] + resid[row*ldres+col]
template <int MODE>
__global__ __launch_bounds__(256, 2) void gemm_bt(
    const bf16_t* __restrict__ A, int lda, long zA,
    const bf16_t* __restrict__ B, int ldb, long zB,
    void* __restrict__ Cv, int ldc, long zC,
    const float* __restrict__ bias,
    const float* __restrict__ resid, int ldres,
    float scale, int K)
{
  __shared__ __align__(16) bf16_t lds_a[128 * 64];
  __shared__ __align__(16) bf16_t lds_b[128 * 64];

  const int tid = threadIdx.x;
  const int lane = tid & 63;
  const int wid = tid >> 6;
  const int wm = (wid >> 1) * 64;
  const int wn = (wid & 1) * 64;
  const int m0 = blockIdx.y * 128;
  const int n0 = blockIdx.x * 128;
  A += (long)blockIdx.z * zA;
  B += (long)blockIdx.z * zB;
  bf16_t* Cb = (bf16_t*)Cv + (long)blockIdx.z * zC;
  float*  Cf = (float*)Cv  + (long)blockIdx.z * zC;

  const bf16_t* gA[4];
  const bf16_t* gB[4];
  int ldsOff[4];
#pragma unroll
  for (int j = 0; j < 4; ++j) {
    int p = j * 256 + tid;          // 16B segment id; lds dst = base + lane*16
    int row = p >> 3;
    int ksl = (p & 7) ^ (row & 7);  // logical k-segment stored at this phys slot
    ldsOff[j] = p * 8;
    gA[j] = A + (long)(m0 + row) * lda + ksl * 8;
    gB[j] = B + (long)(n0 + row) * ldb + ksl * 8;
  }

  f32x4 acc[4][4];
#pragma unroll
  for (int i = 0; i < 4; ++i)
#pragma unroll
    for (int j = 0; j < 4; ++j) acc[i][j] = f32x4{0.f, 0.f, 0.f, 0.f};

  const int q = lane >> 4;
  const int r16 = lane & 15;

  for (int kt = 0; kt < K; kt += 64) {
#pragma unroll
    for (int j = 0; j < 4; ++j) {
      async_copy16(gA[j] + kt, &lds_a[ldsOff[j]]);
      async_copy16(gB[j] + kt, &lds_b[ldsOff[j]]);
    }
    __syncthreads();
#pragma unroll
    for (int s = 0; s < 2; ++s) {
      bf16x8 af[4], bfr[4];
#pragma unroll
      for (int i = 0; i < 4; ++i) {
        int ra = wm + i * 16 + r16;
        int ka = ((s * 4 + q) ^ (ra & 7)) * 8;
        af[i] = *(const bf16x8*)&lds_a[ra * 64 + ka];
        int rb = wn + i * 16 + r16;
        int kb = ((s * 4 + q) ^ (rb & 7)) * 8;
        bfr[i] = *(const bf16x8*)&lds_b[rb * 64 + kb];
      }
#pragma unroll
      for (int i = 0; i < 4; ++i)
#pragma unroll
        for (int j = 0; j < 4; ++j)
          acc[i][j] = __builtin_amdgcn_mfma_f32_16x16x32_bf16(af[i], bfr[j], acc[i][j], 0, 0, 0);
    }
    __syncthreads();
  }

  // C/D layout: col=lane&15, row=(lane>>4)*4+reg  [m89-verified]
#pragma unroll
  for (int i = 0; i < 4; ++i) {
    const int row0 = m0 + wm + i * 16 + q * 4;
#pragma unroll
    for (int j = 0; j < 4; ++j) {
      const int colg = n0 + wn + j * 16 + r16;
      float bv = bias ? bias[colg] : 0.f;
      if (MODE == 0) {
#pragma unroll
        for (int r = 0; r < 4; ++r)
          Cb[(long)(row0 + r) * ldc + colg] = (bf16_t)(acc[i][j][r] * scale + bv);
      } else if (MODE == 1) {
        bf16x4 t;
#pragma unroll
        for (int r = 0; r < 4; ++r) t[r] = (bf16_t)(acc[i][j][r] + bv);
        *(bf16x4*)(Cb + (long)colg * ldc + row0) = t;   // 8B contiguous store
      } else {
#pragma unroll
        for (int r = 0; r < 4; ++r) {
          long rr = row0 + r;
          Cf[rr * ldc + colg] = acc[i][j][r] + bv + resid[rr * ldres + colg];
        }
      }
    }
  }
}

// Row softmax in place on bf16 [rows x 2048]; one block per row.
__global__ __launch_bounds__(256) void softmax_rows(bf16_t* __restrict__ S) {
  bf16_t* p = S + (long)blockIdx.x * 2048;
  const int tid = threadIdx.x;
  const int lane = tid & 63;
  const int wid = tid >> 6;

  bf16x8 v = *(const bf16x8*)&p[tid * 8];
  float f[8];
#pragma unroll
  for (int i = 0; i < 8; ++i) f[i] = (float)v[i];

  float m = f[0];
#pragma unroll
  for (int i = 1; i < 8; ++i) m = fmaxf(m, f[i]);
  for (int off = 32; off; off >>= 1) m = fmaxf(m, __shfl_xor(m, off, 64));
  __shared__ float redm[4], reds[4];
  if (lane == 0) redm[wid] = m;
  __syncthreads();
  m = fmaxf(fmaxf(redm[0], redm[1]), fmaxf(redm[2], redm[3]));

  float s = 0.f;
#pragma unroll
  for (int i = 0; i < 8; ++i) { f[i] = __expf(f[i] - m); s += f[i]; }
  for (int off = 32; off; off >>= 1) s += __shfl_xor(s, off, 64);
  if (lane == 0) reds[wid] = s;
  __syncthreads();
  s = reds[0] + reds[1] + reds[2] + reds[3];
  const float inv = 1.f / s;

  bf16x8 o;
#pragma unroll
  for (int i = 0; i < 8; ++i) o[i] = (bf16_t)(f[i] * inv);
  *(bf16x8*)&p[tid * 8] = o;
}

extern "C" void kernel_launch(void* const* d_in, const int* in_sizes, int n_in,
                              void* d_out, int out_size, void* d_ws, size_t ws_size,
                              hipStream_t stream)
{
  (void)in_sizes; (void)n_in; (void)out_size;
  const int N = 2048, D = 512, HD = 4096;

  const float* img_f  = (const float*)d_in[0];
  const float* meta_f = (const float*)d_in[1];
  float* out = (float*)d_out;               // [N, 1024] fp32

  // bf16 scratch layout
  bf16_t* p = (bf16_t*)d_ws;
  bf16_t* imgb  = p; p += (size_t)N * D;    // 2 MB
  bf16_t* metab = p; p += (size_t)N * D;    // 2 MB
  bf16_t* wq = p; p += (size_t)HD * D;      // 4 MB (reused per dir)
  bf16_t* wk = p; p += (size_t)HD * D;
  bf16_t* wv = p; p += (size_t)HD * D;
  bf16_t* wl = p; p += (size_t)HD * D;
  bf16_t* qcat = p; p += (size_t)N * HD;    // 16 MB
  bf16_t* kcat = p; p += (size_t)N * HD;
  bf16_t* vt   = p; p += (size_t)N * HD;    // [8][512][2048] V^T per head
  bf16_t* res  = p; p += (size_t)N * HD;
  bf16_t* S    = p;                          // hb * N * N
  size_t fixed_bytes = (size_t)((char*)S - (char*)d_ws);
  int hb = 8;                                // heads per score batch
  while (hb > 1 && fixed_bytes + (size_t)hb * N * N * sizeof(bf16_t) > ws_size) hb >>= 1;

  const float rs = 1.f / sqrtf((float)D);
  dim3 blk(256);

  cast_f32_bf16<<<dim3(N * D / 1024), blk, 0, stream>>>(img_f, imgb, N * D);
  cast_f32_bf16<<<dim3(N * D / 1024), blk, 0, stream>>>(meta_f, metab, N * D);

  for (int dir = 0; dir < 2; ++dir) {
    const bf16_t* Xq    = dir ? imgb  : metab;
    const bf16_t* Xkv   = dir ? metab : imgb;
    const float*  resid = dir ? meta_f : img_f;
    const float* Wq_f = (const float*)d_in[dir ? 8  : 2];
    const float* bq_f = (const float*)d_in[dir ? 9  : 3];
    const float* Wk_f = (const float*)d_in[dir ? 10 : 4];
    const float* bk_f = (const float*)d_in[dir ? 11 : 5];
    const float* Wv_f = (const float*)d_in[dir ? 12 : 6];
    const float* bv_f = (const float*)d_in[dir ? 13 : 7];
    const float* Wl_f = (const float*)d_in[dir ? 16 : 14];
    const float* bl_f = (const float*)d_in[dir ? 17 : 15];

    const int nw = HD * D;                  // 2,097,152 elements per weight
    cast_f32_bf16<<<dim3(nw / 1024), blk, 0, stream>>>(Wq_f, wq, nw);
    cast_f32_bf16<<<dim3(nw / 1024), blk, 0, stream>>>(Wk_f, wk, nw);
    cast_f32_bf16<<<dim3(nw / 1024), blk, 0, stream>>>(Wv_f, wv, nw);
    cast_f32_bf16<<<dim3(nw / 1024), blk, 0, stream>>>(Wl_f, wl, nw);

    // projections: X[N,512] @ Wflat[4096,512]^T + b -> [N,4096]
    gemm_bt<0><<<dim3(32, 16, 1), blk, 0, stream>>>(
        Xq,  D, 0, wq, D, 0, qcat, HD, 0, bq_f, nullptr, 0, 1.f, D);
    gemm_bt<0><<<dim3(32, 16, 1), blk, 0, stream>>>(
        Xkv, D, 0, wk, D, 0, kcat, HD, 0, bk_f, nullptr, 0, 1.f, D);
    gemm_bt<1><<<dim3(32, 16, 1), blk, 0, stream>>>(
        Xkv, D, 0, wv, D, 0, vt, N, 0, bv_f, nullptr, 0, 1.f, D);   // V^T

    for (int b = 0; b < 8; b += hb) {
      // S[z] = (Q_{b+z} @ K_{b+z}^T) / sqrt(512)
      gemm_bt<0><<<dim3(16, 16, hb), blk, 0, stream>>>(
          qcat + (size_t)b * D, HD, D, kcat + (size_t)b * D, HD, D,
          S, N, (long)N * N, nullptr, nullptr, 0, rs, D);

      softmax_rows<<<dim3(hb * N), blk, 0, stream>>>(S);

      // res[:, (b+z)*512:] = P @ V  (= P @ (V^T)^T)
      gemm_bt<0><<<dim3(4, 16, hb), blk, 0, stream>>>(
          S, N, (long)N * N, vt + (size_t)b * D * N, N, (long)D * N,
          res + (size_t)b * D, HD, D, nullptr, nullptr, 0, 1.f, N);
    }

    // out[:, dir*512:] = res @ W_lin^T + b_lin + resid   (fp32 store)
    gemm_bt<2><<<dim3(4, 16, 1), blk, 0, stream>>>(
        res, HD, 0, wl, HD, 0, out + dir * D, 2 * D, 0,
        bl_f, resid, D, 1.f, HD);
  }
}

// Round 3
// 510.260 us; speedup vs baseline: 1.1774x; 1.1774x over previous
//
#include <hip/hip_runtime.h>
#include <math.h>

typedef __bf16 bf16_t;
typedef __attribute__((ext_vector_type(8))) __bf16 bf16x8;
typedef __attribute__((ext_vector_type(4))) __bf16 bf16x4;
typedef __attribute__((ext_vector_type(4))) float f32x4;

#define AS_GLOBAL __attribute__((address_space(1)))
#define AS_LDS    __attribute__((address_space(3)))

__device__ __forceinline__ void async_copy16(const bf16_t* g, bf16_t* l) {
  __builtin_amdgcn_global_load_lds((const AS_GLOBAL void*)g, (AS_LDS void*)l, 16, 0, 0);
}

// up-to-4-way fp32->bf16 cast; blockIdx.y selects source/dest pair.
__global__ __launch_bounds__(256) void cast_f32_bf16_4(
    const float* __restrict__ s0, const float* __restrict__ s1,
    const float* __restrict__ s2, const float* __restrict__ s3,
    bf16_t* __restrict__ d0, bf16_t* __restrict__ d1,
    bf16_t* __restrict__ d2, bf16_t* __restrict__ d3, int n) {
  const float* s; bf16_t* d;
  switch (blockIdx.y) {
    case 0:  s = s0; d = d0; break;
    case 1:  s = s1; d = d1; break;
    case 2:  s = s2; d = d2; break;
    default: s = s3; d = d3; break;
  }
  int i = (blockIdx.x * 256 + threadIdx.x) * 4;
  if (i >= n) return;
  float4 v = *(const float4*)(s + i);
  bf16x4 o;
  o[0] = (bf16_t)v.x; o[1] = (bf16_t)v.y; o[2] = (bf16_t)v.z; o[3] = (bf16_t)v.w;
  *(bf16x4*)(d + i) = o;
}

// C[M x Ncols] = A[M x K] @ B[Ncols x K]^T   (A,B bf16 row-major)
// 128x128 tile, BK=64, 256 threads (4 waves), mfma 16x16x32 bf16.
// global_load_lds(16B) staging with XOR swizzle -> conflict-free ds_read_b128.
// MODE 0: bf16 C[row*ldc+col] = acc*scale + bias[col]
// MODE 3: f32  C[row*ldc+col] = acc                     (split-K partial; z = k-split)
// MODE 4: cols [0,4096): bf16 C[row*ldc+col] = acc + bias[col]
//         cols [4096,8192): bf16 C2[(col-4096)*N + row] = acc + bias2[col-4096]  (V^T)
template <int MODE>
__global__ __launch_bounds__(256, 2) void gemm_bt(
    const bf16_t* __restrict__ A, int lda, long zA,
    const bf16_t* __restrict__ B, int ldb, long zB,
    void* __restrict__ Cv, int ldc, long zC,
    void* __restrict__ C2v, const float* __restrict__ bias2,
    const float* __restrict__ bias,
    float scale, int K)
{
  __shared__ __align__(16) bf16_t lds_a[128 * 64];
  __shared__ __align__(16) bf16_t lds_b[128 * 64];

  const int tid = threadIdx.x;
  const int lane = tid & 63;
  const int wid = tid >> 6;
  const int wm = (wid >> 1) * 64;
  const int wn = (wid & 1) * 64;
  const int m0 = blockIdx.y * 128;
  const int n0 = blockIdx.x * 128;
  A += (long)blockIdx.z * zA;   // MODE 3: zA = k-offset per split
  B += (long)blockIdx.z * zB;
  bf16_t* Cb = (bf16_t*)Cv + (long)blockIdx.z * zC;
  float*  Cf = (float*)Cv  + (long)blockIdx.z * zC;
  bf16_t* C2 = (bf16_t*)C2v;

  const bf16_t* gA[4];
  const bf16_t* gB[4];
  int ldsOff[4];
#pragma unroll
  for (int j = 0; j < 4; ++j) {
    int p = j * 256 + tid;          // 16B segment id; lds dst = base + lane*16
    int row = p >> 3;
    int ksl = (p & 7) ^ (row & 7);
    ldsOff[j] = p * 8;
    gA[j] = A + (long)(m0 + row) * lda + ksl * 8;
    gB[j] = B + (long)(n0 + row) * ldb + ksl * 8;
  }

  f32x4 acc[4][4];
#pragma unroll
  for (int i = 0; i < 4; ++i)
#pragma unroll
    for (int j = 0; j < 4; ++j) acc[i][j] = f32x4{0.f, 0.f, 0.f, 0.f};

  const int q = lane >> 4;
  const int r16 = lane & 15;

  for (int kt = 0; kt < K; kt += 64) {
#pragma unroll
    for (int j = 0; j < 4; ++j) {
      async_copy16(gA[j] + kt, &lds_a[ldsOff[j]]);
      async_copy16(gB[j] + kt, &lds_b[ldsOff[j]]);
    }
    __syncthreads();
#pragma unroll
    for (int s = 0; s < 2; ++s) {
      bf16x8 af[4], bfr[4];
#pragma unroll
      for (int i = 0; i < 4; ++i) {
        int ra = wm + i * 16 + r16;
        int ka = ((s * 4 + q) ^ (ra & 7)) * 8;
        af[i] = *(const bf16x8*)&lds_a[ra * 64 + ka];
        int rb = wn + i * 16 + r16;
        int kb = ((s * 4 + q) ^ (rb & 7)) * 8;
        bfr[i] = *(const bf16x8*)&lds_b[rb * 64 + kb];
      }
#pragma unroll
      for (int i = 0; i < 4; ++i)
#pragma unroll
        for (int j = 0; j < 4; ++j)
          acc[i][j] = __builtin_amdgcn_mfma_f32_16x16x32_bf16(af[i], bfr[j], acc[i][j], 0, 0, 0);
    }
    __syncthreads();
  }

  // C/D layout: col=lane&15, row=(lane>>4)*4+reg  [m89-verified]
#pragma unroll
  for (int i = 0; i < 4; ++i) {
    const int row0 = m0 + wm + i * 16 + q * 4;
#pragma unroll
    for (int j = 0; j < 4; ++j) {
      const int colg = n0 + wn + j * 16 + r16;
      if (MODE == 0) {
        float bv = bias ? bias[colg] : 0.f;
#pragma unroll
        for (int r = 0; r < 4; ++r)
          Cb[(long)(row0 + r) * ldc + colg] = (bf16_t)(acc[i][j][r] * scale + bv);
      } else if (MODE == 3) {
#pragma unroll
        for (int r = 0; r < 4; ++r)
          Cf[(long)(row0 + r) * ldc + colg] = acc[i][j][r];
      } else {  // MODE 4
        if (n0 < 4096) {
          float bv = bias[colg];
#pragma unroll
          for (int r = 0; r < 4; ++r)
            Cb[(long)(row0 + r) * ldc + colg] = (bf16_t)(acc[i][j][r] + bv);
        } else {
          int vcol = colg - 4096;
          float bv = bias2[vcol];
          bf16x4 t;
#pragma unroll
          for (int r = 0; r < 4; ++r) t[r] = (bf16_t)(acc[i][j][r] + bv);
          *(bf16x4*)(C2 + (long)vcol * 2048 + row0) = t;   // 8B contiguous store
        }
      }
    }
  }
}

// Row softmax in place on bf16 [rows x 2048]; one block per row.
__global__ __launch_bounds__(256) void softmax_rows(bf16_t* __restrict__ S) {
  bf16_t* p = S + (long)blockIdx.x * 2048;
  const int tid = threadIdx.x;
  const int lane = tid & 63;
  const int wid = tid >> 6;

  bf16x8 v = *(const bf16x8*)&p[tid * 8];
  float f[8];
#pragma unroll
  for (int i = 0; i < 8; ++i) f[i] = (float)v[i];

  float m = f[0];
#pragma unroll
  for (int i = 1; i < 8; ++i) m = fmaxf(m, f[i]);
  for (int off = 32; off; off >>= 1) m = fmaxf(m, __shfl_xor(m, off, 64));
  __shared__ float redm[4], reds[4];
  if (lane == 0) redm[wid] = m;
  __syncthreads();
  m = fmaxf(fmaxf(redm[0], redm[1]), fmaxf(redm[2], redm[3]));

  float s = 0.f;
#pragma unroll
  for (int i = 0; i < 8; ++i) { f[i] = __expf(f[i] - m); s += f[i]; }
  for (int off = 32; off; off >>= 1) s += __shfl_xor(s, off, 64);
  if (lane == 0) reds[wid] = s;
  __syncthreads();
  s = reds[0] + reds[1] + reds[2] + reds[3];
  const float inv = 1.f / s;

  bf16x8 o;
#pragma unroll
  for (int i = 0; i < 8; ++i) o[i] = (bf16_t)(f[i] * inv);
  *(bf16x8*)&p[tid * 8] = o;
}

// out[row*1024+col] = sum_s part[s][row][col] + bias[col] + resid[row*512+col]
__global__ __launch_bounds__(256) void reduce_splitk(
    const float* __restrict__ part, const float* __restrict__ bias,
    const float* __restrict__ resid, float* __restrict__ out, int splits) {
  int i = blockIdx.x * 256 + threadIdx.x;     // over 2048*512/4 float4 groups
  int row = i >> 7;
  int col = (i & 127) * 4;
  float4 a = *(const float4*)(resid + (long)row * 512 + col);
  float4 b = *(const float4*)(bias + col);
  a.x += b.x; a.y += b.y; a.z += b.z; a.w += b.w;
  for (int s = 0; s < splits; ++s) {
    float4 p = *(const float4*)(part + (long)s * 2048 * 512 + (long)row * 512 + col);
    a.x += p.x; a.y += p.y; a.z += p.z; a.w += p.w;
  }
  *(float4*)(out + (long)row * 1024 + col) = a;
}

extern "C" void kernel_launch(void* const* d_in, const int* in_sizes, int n_in,
                              void* d_out, int out_size, void* d_ws, size_t ws_size,
                              hipStream_t stream)
{
  (void)in_sizes; (void)n_in; (void)out_size;
  const int N = 2048, D = 512, HD = 4096;
  const int NW = HD * D;                      // 2,097,152 elements per weight

  const float* img_f  = (const float*)d_in[0];
  const float* meta_f = (const float*)d_in[1];
  float* out = (float*)d_out;                 // [N, 1024] fp32

  // bf16 scratch layout (same footprint as round 2: 84.4 MB fixed + hb*8.4 MB)
  bf16_t* p = (bf16_t*)d_ws;
  bf16_t* imgb  = p; p += (size_t)N * D;
  bf16_t* metab = p; p += (size_t)N * D;
  bf16_t* wq  = p; p += (size_t)NW;           // 4 MB
  bf16_t* wkv = p; p += (size_t)2 * NW;       // 8 MB ([Wk;Wv] stacked)
  bf16_t* wl  = p; p += (size_t)NW;           // 4 MB
  bf16_t* qcat = p; p += (size_t)N * HD;      // 16 MB
  bf16_t* kcat = p; p += (size_t)N * HD;
  bf16_t* vt   = p; p += (size_t)N * HD;      // [8][512][2048] V^T per head
  bf16_t* res  = p; p += (size_t)N * HD;
  bf16_t* S    = p;                           // hb * N * N bf16; reused as split-K f32 partials
  size_t fixed_bytes = (size_t)((char*)S - (char*)d_ws);
  int hb = 8;
  while (hb > 1 && fixed_bytes + (size_t)hb * N * N * sizeof(bf16_t) > ws_size) hb >>= 1;
  const int splits = (hb >= 4) ? 8 : 2 * hb;  // splits*4MB <= hb*8MB capacity at S
  const int Ks = HD / splits;

  const float rs = 1.f / sqrtf((float)D);
  dim3 blk(256);

  cast_f32_bf16_4<<<dim3(N * D / 1024, 2), blk, 0, stream>>>(
      img_f, meta_f, nullptr, nullptr, imgb, metab, nullptr, nullptr, N * D);

  for (int dir = 0; dir < 2; ++dir) {
    const bf16_t* Xq    = dir ? imgb  : metab;
    const bf16_t* Xkv   = dir ? metab : imgb;
    const float*  resid = dir ? meta_f : img_f;
    const float* Wq_f = (const float*)d_in[dir ? 8  : 2];
    const float* bq_f = (const float*)d_in[dir ? 9  : 3];
    const float* Wk_f = (const float*)d_in[dir ? 10 : 4];
    const float* bk_f = (const float*)d_in[dir ? 11 : 5];
    const float* Wv_f = (const float*)d_in[dir ? 12 : 6];
    const float* bv_f = (const float*)d_in[dir ? 13 : 7];
    const float* Wl_f = (const float*)d_in[dir ? 16 : 14];
    const float* bl_f = (const float*)d_in[dir ? 17 : 15];

    // cast all 4 weight matrices (each NW elements) in one dispatch
    cast_f32_bf16_4<<<dim3(NW / 1024, 4), blk, 0, stream>>>(
        Wq_f, Wk_f, Wv_f, Wl_f, wq, wkv, wkv + NW, wl, NW);

    // Q projection: Xq[N,512] @ Wq[4096,512]^T + bq -> qcat [N,4096]
    gemm_bt<0><<<dim3(32, 16, 1), blk, 0, stream>>>(
        Xq, D, 0, wq, D, 0, qcat, HD, 0, nullptr, nullptr, bq_f, 1.f, D);
    // K+V merged: Xkv @ [Wk;Wv][8192,512]^T -> kcat (cols<4096) / vt transposed
    gemm_bt<4><<<dim3(64, 16, 1), blk, 0, stream>>>(
        Xkv, D, 0, wkv, D, 0, kcat, HD, 0, vt, bv_f, bk_f, 1.f, D);

    for (int b = 0; b < 8; b += hb) {
      gemm_bt<0><<<dim3(16, 16, hb), blk, 0, stream>>>(
          qcat + (size_t)b * D, HD, D, kcat + (size_t)b * D, HD, D,
          S, N, (long)N * N, nullptr, nullptr, nullptr, rs, D);

      softmax_rows<<<dim3(hb * N), blk, 0, stream>>>(S);

      gemm_bt<0><<<dim3(4, 16, hb), blk, 0, stream>>>(
          S, N, (long)N * N, vt + (size_t)b * D * N, N, (long)D * N,
          res + (size_t)b * D, HD, D, nullptr, nullptr, nullptr, 1.f, N);
    }

    // output linear, split-K: partial[s] = res[:, s*Ks:(s+1)*Ks] @ Wl[:, s*Ks:]^T
    float* part = (float*)S;
    gemm_bt<3><<<dim3(4, 16, splits), blk, 0, stream>>>(
        res, HD, Ks, wl, HD, Ks, part, 512, (long)N * 512,
        nullptr, nullptr, nullptr, 1.f, Ks);
    reduce_splitk<<<dim3(1024), blk, 0, stream>>>(
        part, bl_f, resid, out + dir * D, splits);
  }
}

// Round 5
// 466.852 us; speedup vs baseline: 1.2869x; 1.0930x over previous
//
#include <hip/hip_runtime.h>
#include <math.h>

typedef __bf16 bf16_t;
typedef __attribute__((ext_vector_type(8))) __bf16 bf16x8;
typedef __attribute__((ext_vector_type(4))) __bf16 bf16x4;
typedef __attribute__((ext_vector_type(4))) float f32x4;

#define AS_GLOBAL __attribute__((address_space(1)))
#define AS_LDS    __attribute__((address_space(3)))

__device__ __forceinline__ void async_copy16(const bf16_t* g, bf16_t* l) {
  __builtin_amdgcn_global_load_lds((const AS_GLOBAL void*)g, (AS_LDS void*)l, 16, 0, 0);
}

// up-to-4-way fp32->bf16 cast; blockIdx.y selects source/dest pair.
__global__ __launch_bounds__(256) void cast_f32_bf16_4(
    const float* __restrict__ s0, const float* __restrict__ s1,
    const float* __restrict__ s2, const float* __restrict__ s3,
    bf16_t* __restrict__ d0, bf16_t* __restrict__ d1,
    bf16_t* __restrict__ d2, bf16_t* __restrict__ d3, int n) {
  const float* s; bf16_t* d;
  switch (blockIdx.y) {
    case 0:  s = s0; d = d0; break;
    case 1:  s = s1; d = d1; break;
    case 2:  s = s2; d = d2; break;
    default: s = s3; d = d3; break;
  }
  int i = (blockIdx.x * 256 + threadIdx.x) * 4;
  if (i >= n) return;
  float4 v = *(const float4*)(s + i);
  bf16x4 o;
  o[0] = (bf16_t)v.x; o[1] = (bf16_t)v.y; o[2] = (bf16_t)v.z; o[3] = (bf16_t)v.w;
  *(bf16x4*)(d + i) = o;
}

// C[M x Ncols] = A[M x K] @ B[Ncols x K]^T   (A,B bf16 row-major)
// 128x128 tile, BK=64, 256 threads (4 waves), mfma 16x16x32 bf16,
// global_load_lds(16B) staging with XOR swizzle -> conflict-free ds_read_b128.
// MODE 2 (QK):  bf16 C = exp(acc*scale); per-(row,colblock) partial rowsums ->
//               partial[(z*gridDim.x + bx)*2048 + row]
// MODE 3 (spK): f32 C[row*ldc+col] = acc   (z = k-split, zA/zB = k-offset)
// MODE 4 (proj): A-switch: n0<4096 uses A (Xq), else A2 (Xkv).
//               cols [0,4096):     bf16 C [row*ldc + c]        = acc + bias_q[c]   (qcat)
//               cols [4096,8192):  bf16 C3[row*ldc + (c-4096)] = acc + bias_k[...] (kcat)
//               cols [8192,12288): bf16 C2[(c-8192)*2048+row]  = acc + bias_v[...] (V^T)
// MODE 5 (PV):  bf16 C = acc * invl[z*2048 + row]   (invl passed via bias_q)
template <int MODE>
__global__ __launch_bounds__(256, 2) void gemm_bt(
    const bf16_t* __restrict__ A, int lda, long zA,
    const bf16_t* __restrict__ B, int ldb, long zB,
    void* __restrict__ Cv, int ldc, long zC,
    void* __restrict__ C2v,
    void* __restrict__ C3v,
    const float* __restrict__ bias_q,
    const float* __restrict__ bias_k,
    const float* __restrict__ bias_v,
    float* __restrict__ partial,
    const bf16_t* __restrict__ A2,
    float scale, int K)
{
  __shared__ __align__(16) bf16_t lds_a[128 * 64];
  __shared__ __align__(16) bf16_t lds_b[128 * 64];

  const int tid = threadIdx.x;
  const int lane = tid & 63;
  const int wid = tid >> 6;
  const int wm = (wid >> 1) * 64;
  const int wn = (wid & 1) * 64;
  const int m0 = blockIdx.y * 128;
  const int n0 = blockIdx.x * 128;
  const bf16_t* Ap = A;
  if (MODE == 4 && n0 >= 4096) Ap = A2;
  Ap += (long)blockIdx.z * zA;
  B += (long)blockIdx.z * zB;
  bf16_t* Cb = (bf16_t*)Cv + (long)blockIdx.z * zC;
  float*  Cf = (float*)Cv  + (long)blockIdx.z * zC;
  bf16_t* C2 = (bf16_t*)C2v;
  bf16_t* C3 = (bf16_t*)C3v;

  const bf16_t* gA[4];
  const bf16_t* gB[4];
  int ldsOff[4];
#pragma unroll
  for (int j = 0; j < 4; ++j) {
    int p = j * 256 + tid;          // 16B segment id; lds dst = base + lane*16
    int row = p >> 3;
    int ksl = (p & 7) ^ (row & 7);
    ldsOff[j] = p * 8;
    gA[j] = Ap + (long)(m0 + row) * lda + ksl * 8;
    gB[j] = B + (long)(n0 + row) * ldb + ksl * 8;
  }

  f32x4 acc[4][4];
#pragma unroll
  for (int i = 0; i < 4; ++i)
#pragma unroll
    for (int j = 0; j < 4; ++j) acc[i][j] = f32x4{0.f, 0.f, 0.f, 0.f};

  const int q = lane >> 4;
  const int r16 = lane & 15;

  for (int kt = 0; kt < K; kt += 64) {
#pragma unroll
    for (int j = 0; j < 4; ++j) {
      async_copy16(gA[j] + kt, &lds_a[ldsOff[j]]);
      async_copy16(gB[j] + kt, &lds_b[ldsOff[j]]);
    }
    __syncthreads();
#pragma unroll
    for (int s = 0; s < 2; ++s) {
      bf16x8 af[4], bfr[4];
#pragma unroll
      for (int i = 0; i < 4; ++i) {
        int ra = wm + i * 16 + r16;
        int ka = ((s * 4 + q) ^ (ra & 7)) * 8;
        af[i] = *(const bf16x8*)&lds_a[ra * 64 + ka];
        int rb = wn + i * 16 + r16;
        int kb = ((s * 4 + q) ^ (rb & 7)) * 8;
        bfr[i] = *(const bf16x8*)&lds_b[rb * 64 + kb];
      }
#pragma unroll
      for (int i = 0; i < 4; ++i)
#pragma unroll
        for (int j = 0; j < 4; ++j)
          acc[i][j] = __builtin_amdgcn_mfma_f32_16x16x32_bf16(af[i], bfr[j], acc[i][j], 0, 0, 0);
    }
    __syncthreads();
  }

  // C/D layout: col=lane&15, row=(lane>>4)*4+reg  [m89-verified]
  if (MODE == 2) {
    float rowsum[4][4];
#pragma unroll
    for (int i = 0; i < 4; ++i)
#pragma unroll
      for (int r = 0; r < 4; ++r) rowsum[i][r] = 0.f;
#pragma unroll
    for (int i = 0; i < 4; ++i) {
      const int row0 = m0 + wm + i * 16 + q * 4;
#pragma unroll
      for (int j = 0; j < 4; ++j) {
        const int colg = n0 + wn + j * 16 + r16;
#pragma unroll
        for (int r = 0; r < 4; ++r) {
          float pv = __expf(acc[i][j][r] * scale);
          Cb[(long)(row0 + r) * ldc + colg] = (bf16_t)pv;
          rowsum[i][r] += pv;
        }
      }
    }
    // reduce over the 16 lanes (r16 group) holding this row's 64 cols
#pragma unroll
    for (int m = 1; m <= 8; m <<= 1)
#pragma unroll
      for (int i = 0; i < 4; ++i)
#pragma unroll
        for (int r = 0; r < 4; ++r)
          rowsum[i][r] += __shfl_xor(rowsum[i][r], m, 64);
    float* lsum = (float*)lds_a;   // safe: loop-end barrier drained all LDS reads
    if (r16 == 0) {
#pragma unroll
      for (int i = 0; i < 4; ++i)
#pragma unroll
        for (int r = 0; r < 4; ++r)
          lsum[(wm + i * 16 + q * 4 + r) * 2 + (wid & 1)] = rowsum[i][r];
    }
    __syncthreads();
    if (tid < 128) {
      float s = lsum[tid * 2] + lsum[tid * 2 + 1];
      partial[((long)blockIdx.z * gridDim.x + blockIdx.x) * 2048 + m0 + tid] = s;
    }
    return;
  }

#pragma unroll
  for (int i = 0; i < 4; ++i) {
    const int row0 = m0 + wm + i * 16 + q * 4;
    float w[4];
    if (MODE == 5) {
      const float* il = bias_q + (long)blockIdx.z * 2048;
#pragma unroll
      for (int r = 0; r < 4; ++r) w[r] = il[row0 + r];
    }
#pragma unroll
    for (int j = 0; j < 4; ++j) {
      const int colg = n0 + wn + j * 16 + r16;
      if (MODE == 3) {
#pragma unroll
        for (int r = 0; r < 4; ++r)
          Cf[(long)(row0 + r) * ldc + colg] = acc[i][j][r];
      } else if (MODE == 5) {
#pragma unroll
        for (int r = 0; r < 4; ++r)
          Cb[(long)(row0 + r) * ldc + colg] = (bf16_t)(acc[i][j][r] * w[r]);
      } else {  // MODE 4
        if (n0 < 4096) {
          float bv = bias_q[colg];
#pragma unroll
          for (int r = 0; r < 4; ++r)
            Cb[(long)(row0 + r) * ldc + colg] = (bf16_t)(acc[i][j][r] + bv);
        } else if (n0 < 8192) {
          int kc = colg - 4096;
          float bv = bias_k[kc];
#pragma unroll
          for (int r = 0; r < 4; ++r)
            C3[(long)(row0 + r) * ldc + kc] = (bf16_t)(acc[i][j][r] + bv);  // kcat
        } else {
          int vcol = colg - 8192;
          float bv = bias_v[vcol];
          bf16x4 t;
#pragma unroll
          for (int r = 0; r < 4; ++r) t[r] = (bf16_t)(acc[i][j][r] + bv);
          *(bf16x4*)(C2 + (long)vcol * 2048 + row0) = t;   // 8B contiguous (V^T)
        }
      }
    }
  }
}

// invl[z][row] = 1 / sum_b partial[z][b][row]
__global__ __launch_bounds__(256) void combine_invl(
    const float* __restrict__ partial, float* __restrict__ invl, int nblk) {
  int t = blockIdx.x * 256 + threadIdx.x;
  int z = t >> 11, row = t & 2047;
  const float* p = partial + ((long)z * nblk) * 2048 + row;
  float s = 0.f;
  for (int b = 0; b < nblk; ++b) s += p[(long)b * 2048];
  invl[t] = 1.f / s;
}

// out[row*1024+col] = sum_s part[s][row][col] + bias[col] + resid[row*512+col]
__global__ __launch_bounds__(256) void reduce_splitk(
    const float* __restrict__ part, const float* __restrict__ bias,
    const float* __restrict__ resid, float* __restrict__ out, int splits) {
  int i = blockIdx.x * 256 + threadIdx.x;
  int row = i >> 7;
  int col = (i & 127) * 4;
  float4 a = *(const float4*)(resid + (long)row * 512 + col);
  float4 b = *(const float4*)(bias + col);
  a.x += b.x; a.y += b.y; a.z += b.z; a.w += b.w;
  for (int s = 0; s < splits; ++s) {
    float4 p = *(const float4*)(part + (long)s * 2048 * 512 + (long)row * 512 + col);
    a.x += p.x; a.y += p.y; a.z += p.z; a.w += p.w;
  }
  *(float4*)(out + (long)row * 1024 + col) = a;
}

extern "C" void kernel_launch(void* const* d_in, const int* in_sizes, int n_in,
                              void* d_out, int out_size, void* d_ws, size_t ws_size,
                              hipStream_t stream)
{
  (void)in_sizes; (void)n_in; (void)out_size;
  const int N = 2048, D = 512, HD = 4096;
  const int NW = HD * D;

  const float* img_f  = (const float*)d_in[0];
  const float* meta_f = (const float*)d_in[1];
  float* out = (float*)d_out;

  bf16_t* p = (bf16_t*)d_ws;
  bf16_t* imgb  = p; p += (size_t)N * D;
  bf16_t* metab = p; p += (size_t)N * D;
  bf16_t* wqkv = p; p += (size_t)3 * NW;      // [Wq;Wk;Wv] stacked, 12 MB
  bf16_t* wl   = p; p += (size_t)NW;
  bf16_t* qcat = p; p += (size_t)N * HD;
  bf16_t* kcat = p; p += (size_t)N * HD;
  bf16_t* vt   = p; p += (size_t)N * HD;      // [8][512][2048] V^T per head
  bf16_t* res  = p; p += (size_t)N * HD;
  bf16_t* S    = p;
  size_t fixed_bytes = (size_t)((char*)S - (char*)d_ws);
  int hb = 8;
  while (hb > 1 && fixed_bytes + (size_t)hb * N * N * sizeof(bf16_t) > ws_size) hb >>= 1;
  const int splits = (hb >= 4) ? 8 : 2 * hb;
  const int Ks = HD / splits;

  // partial rowsums + invl alias the wqkv region: wqkv's last read is the
  // projection GEMM; partial/invl live only between QK and PV of the same dir.
  float* partial = (float*)wqkv;              // [hb][16][2048] floats, 1 MB
  float* invl    = partial + (size_t)8 * 16 * 2048;  // [hb][2048]

  const float rs = 1.f / sqrtf((float)D);
  dim3 blk(256);

  cast_f32_bf16_4<<<dim3(N * D / 1024, 2), blk, 0, stream>>>(
      img_f, meta_f, nullptr, nullptr, imgb, metab, nullptr, nullptr, N * D);

  for (int dir = 0; dir < 2; ++dir) {
    const bf16_t* Xq    = dir ? imgb  : metab;
    const bf16_t* Xkv   = dir ? metab : imgb;
    const float*  resid = dir ? meta_f : img_f;
    const float* Wq_f = (const float*)d_in[dir ? 8  : 2];
    const float* bq_f = (const float*)d_in[dir ? 9  : 3];
    const float* Wk_f = (const float*)d_in[dir ? 10 : 4];
    const float* bk_f = (const float*)d_in[dir ? 11 : 5];
    const float* Wv_f = (const float*)d_in[dir ? 12 : 6];
    const float* bv_f = (const float*)d_in[dir ? 13 : 7];
    const float* Wl_f = (const float*)d_in[dir ? 16 : 14];
    const float* bl_f = (const float*)d_in[dir ? 17 : 15];

    cast_f32_bf16_4<<<dim3(NW / 1024, 4), blk, 0, stream>>>(
        Wq_f, Wk_f, Wv_f, Wl_f, wqkv, wqkv + NW, wqkv + 2 * (size_t)NW, wl, NW);

    // merged projections: [Xq|Xkv] @ [Wq;Wk;Wv]^T -> qcat / kcat / vt
    gemm_bt<4><<<dim3(96, 16, 1), blk, 0, stream>>>(
        Xq, D, 0, wqkv, D, 0, qcat, HD, 0, vt, kcat,
        bq_f, bk_f, bv_f, nullptr, Xkv, 1.f, D);

    for (int b = 0; b < 8; b += hb) {
      // S = exp(Q K^T / sqrt(512)) + partial rowsums
      gemm_bt<2><<<dim3(16, 16, hb), blk, 0, stream>>>(
          qcat + (size_t)b * D, HD, D, kcat + (size_t)b * D, HD, D,
          S, N, (long)N * N, nullptr, nullptr, nullptr, nullptr, nullptr,
          partial, nullptr, rs, D);

      combine_invl<<<dim3(hb * 2048 / 256), blk, 0, stream>>>(partial, invl, 16);

      // res = (S @ V) * invl[row]
      gemm_bt<5><<<dim3(4, 16, hb), blk, 0, stream>>>(
          S, N, (long)N * N, vt + (size_t)b * D * N, N, (long)D * N,
          res + (size_t)b * D, HD, D, nullptr, nullptr,
          invl, nullptr, nullptr, nullptr, nullptr, 1.f, N);
    }

    // output linear, split-K
    float* part = (float*)S;
    gemm_bt<3><<<dim3(4, 16, splits), blk, 0, stream>>>(
        res, HD, Ks, wl, HD, Ks, part, 512, (long)N * 512,
        nullptr, nullptr, nullptr, nullptr, nullptr, nullptr, nullptr, 1.f, Ks);
    reduce_splitk<<<dim3(1024), blk, 0, stream>>>(
        part, bl_f, resid, out + dir * D, splits);
  }
}

// Round 6
// 420.799 us; speedup vs baseline: 1.4277x; 1.1094x over previous
//
#include <hip/hip_runtime.h>
#include <math.h>

typedef __bf16 bf16_t;
typedef unsigned char u8;
typedef long i64;
typedef __attribute__((ext_vector_type(8))) __bf16 bf16x8;
typedef __attribute__((ext_vector_type(4))) __bf16 bf16x4;
typedef __attribute__((ext_vector_type(4))) float f32x4;

#define AS_GLOBAL __attribute__((address_space(1)))
#define AS_LDS    __attribute__((address_space(3)))

__device__ __forceinline__ void async_copy16(const void* g, void* l) {
  __builtin_amdgcn_global_load_lds((const AS_GLOBAL void*)g, (AS_LDS void*)l, 16, 0, 0);
}

__device__ __forceinline__ u8 to_fp8(float v) {
  return (u8)(__builtin_amdgcn_cvt_pk_fp8_f32(v, v, 0, false) & 0xff);
}

// up-to-4-way fp32->bf16 cast; blockIdx.y selects source/dest pair.
__global__ __launch_bounds__(256) void cast_f32_bf16_4(
    const float* __restrict__ s0, const float* __restrict__ s1,
    const float* __restrict__ s2, const float* __restrict__ s3,
    bf16_t* __restrict__ d0, bf16_t* __restrict__ d1,
    bf16_t* __restrict__ d2, bf16_t* __restrict__ d3, int n) {
  const float* s; bf16_t* d;
  switch (blockIdx.y) {
    case 0:  s = s0; d = d0; break;
    case 1:  s = s1; d = d1; break;
    case 2:  s = s2; d = d2; break;
    default: s = s3; d = d3; break;
  }
  int i = (blockIdx.x * 256 + threadIdx.x) * 4;
  if (i >= n) return;
  float4 v = *(const float4*)(s + i);
  bf16x4 o;
  o[0] = (bf16_t)v.x; o[1] = (bf16_t)v.y; o[2] = (bf16_t)v.z; o[3] = (bf16_t)v.w;
  *(bf16x4*)(d + i) = o;
}

// ---------------- bf16 GEMM (projections + split-K output linear) ----------
// C = A[M x K] @ B[N x K]^T. 128x128 tile, BK=64, mfma 16x16x32 bf16.
// MODE 3 (spK): f32 C[row*ldc+col] = acc   (z = k-split; zA/zB = k-offset)
// MODE 4 (proj): A-switch: n0<4096 uses A (Xq), else A2 (Xkv). fp8 outputs:
//   cols [0,4096):     Q8[row*4096 + c]          = fp8(acc + bias_q[c])
//   cols [4096,8192):  K8[row*4096 + (c-4096)]   = fp8(acc + bias_k[..])
//   cols [8192,12288): V8[(c-8192)*2048 + row]   = fp8(acc + bias_v[..]) (V^T)
template <int MODE>
__global__ __launch_bounds__(256, 2) void gemm_bt(
    const bf16_t* __restrict__ A, int lda, long zA,
    const bf16_t* __restrict__ B, int ldb, long zB,
    void* __restrict__ Cv, int ldc, long zC,
    u8* __restrict__ K8, u8* __restrict__ V8,
    const float* __restrict__ bias_q,
    const float* __restrict__ bias_k,
    const float* __restrict__ bias_v,
    const bf16_t* __restrict__ A2,
    float scale, int K)
{
  __shared__ __align__(16) bf16_t lds_a[128 * 64];
  __shared__ __align__(16) bf16_t lds_b[128 * 64];

  const int tid = threadIdx.x;
  const int lane = tid & 63;
  const int wid = tid >> 6;
  const int wm = (wid >> 1) * 64;
  const int wn = (wid & 1) * 64;
  const int m0 = blockIdx.y * 128;
  const int n0 = blockIdx.x * 128;
  const bf16_t* Ap = A;
  if (MODE == 4 && n0 >= 4096) Ap = A2;
  Ap += (long)blockIdx.z * zA;
  B += (long)blockIdx.z * zB;
  u8*    Cb = (u8*)Cv    + (long)blockIdx.z * zC;
  float* Cf = (float*)Cv + (long)blockIdx.z * zC;

  const bf16_t* gA[4];
  const bf16_t* gB[4];
  int ldsOff[4];
#pragma unroll
  for (int j = 0; j < 4; ++j) {
    int p = j * 256 + tid;          // 16B segment; lds dst = base + lane*16
    int row = p >> 3;
    int ksl = (p & 7) ^ (row & 7);  // XOR swizzle
    ldsOff[j] = p * 8;
    gA[j] = Ap + (long)(m0 + row) * lda + ksl * 8;
    gB[j] = B + (long)(n0 + row) * ldb + ksl * 8;
  }

  f32x4 acc[4][4];
#pragma unroll
  for (int i = 0; i < 4; ++i)
#pragma unroll
    for (int j = 0; j < 4; ++j) acc[i][j] = f32x4{0.f, 0.f, 0.f, 0.f};

  const int q = lane >> 4;
  const int r16 = lane & 15;

  for (int kt = 0; kt < K; kt += 64) {
#pragma unroll
    for (int j = 0; j < 4; ++j) {
      async_copy16(gA[j] + kt, &lds_a[ldsOff[j]]);
      async_copy16(gB[j] + kt, &lds_b[ldsOff[j]]);
    }
    __syncthreads();
#pragma unroll
    for (int s = 0; s < 2; ++s) {
      bf16x8 af[4], bfr[4];
#pragma unroll
      for (int i = 0; i < 4; ++i) {
        int ra = wm + i * 16 + r16;
        int ka = ((s * 4 + q) ^ (ra & 7)) * 8;
        af[i] = *(const bf16x8*)&lds_a[ra * 64 + ka];
        int rb = wn + i * 16 + r16;
        int kb = ((s * 4 + q) ^ (rb & 7)) * 8;
        bfr[i] = *(const bf16x8*)&lds_b[rb * 64 + kb];
      }
#pragma unroll
      for (int i = 0; i < 4; ++i)
#pragma unroll
        for (int j = 0; j < 4; ++j)
          acc[i][j] = __builtin_amdgcn_mfma_f32_16x16x32_bf16(af[i], bfr[j], acc[i][j], 0, 0, 0);
    }
    __syncthreads();
  }

  // C/D layout: col=lane&15, row=(lane>>4)*4+reg  [m89-verified]
#pragma unroll
  for (int i = 0; i < 4; ++i) {
    const int row0 = m0 + wm + i * 16 + q * 4;
#pragma unroll
    for (int j = 0; j < 4; ++j) {
      const int colg = n0 + wn + j * 16 + r16;
      if (MODE == 3) {
#pragma unroll
        for (int r = 0; r < 4; ++r)
          Cf[(long)(row0 + r) * ldc + colg] = acc[i][j][r];
      } else {  // MODE 4
        if (n0 < 4096) {
          float bv = bias_q[colg];
#pragma unroll
          for (int r = 0; r < 4; ++r)
            Cb[(long)(row0 + r) * 4096 + colg] = to_fp8(acc[i][j][r] + bv);
        } else if (n0 < 8192) {
          int kc = colg - 4096;
          float bv = bias_k[kc];
#pragma unroll
          for (int r = 0; r < 4; ++r)
            K8[(long)(row0 + r) * 4096 + kc] = to_fp8(acc[i][j][r] + bv);
        } else {
          int vcol = colg - 8192;
          float bv = bias_v[vcol];
          int w = __builtin_amdgcn_cvt_pk_fp8_f32(acc[i][j][0] + bv, acc[i][j][1] + bv, 0, false);
          w = __builtin_amdgcn_cvt_pk_fp8_f32(acc[i][j][2] + bv, acc[i][j][3] + bv, w, true);
          *(int*)(V8 + (long)vcol * 2048 + row0) = w;   // 4 consecutive rows (V^T)
        }
      }
    }
  }
}

// ---------------- fp8 GEMM (attention core), BK=128 ------------------------
// C = A[M x K] @ B[N x K]^T, A/B fp8 e4m3, 128x128 tile, mfma 16x16x32 fp8.
// MODE 0 (QK): S8 = fp8(exp(acc*scale)); fp32 partial rowsums ->
//              partial[(z*gridDim.x+bx)*2048 + row]
// MODE 1 (PV): bf16 C = acc / (sum_b partial[(z*16+b)*2048+row])
template <int MODE>
__global__ __launch_bounds__(256, 2) void gemm_f8(
    const u8* __restrict__ A, int lda, long zA,
    const u8* __restrict__ B, int ldb, long zB,
    void* __restrict__ Cv, int ldc, long zC,
    float* __restrict__ partial,
    float scale, int K)
{
  __shared__ __align__(16) u8 lds_a[128 * 128];
  __shared__ __align__(16) u8 lds_b[128 * 128];

  const int tid = threadIdx.x;
  const int lane = tid & 63;
  const int wid = tid >> 6;
  const int wm = (wid >> 1) * 64;
  const int wn = (wid & 1) * 64;
  const int m0 = blockIdx.y * 128;
  const int n0 = blockIdx.x * 128;
  A += (long)blockIdx.z * zA;
  B += (long)blockIdx.z * zB;
  u8*     C8 = (u8*)Cv     + (long)blockIdx.z * zC;
  bf16_t* Cb = (bf16_t*)Cv + (long)blockIdx.z * zC;

  // tile = 128 rows x 128 bytes = 1024 16B-segments; 4 per thread, swizzled
  const u8* gA[4];
  const u8* gB[4];
  int ldsOff[4];
#pragma unroll
  for (int j = 0; j < 4; ++j) {
    int p = j * 256 + tid;
    int row = p >> 3;
    int ksl = (p & 7) ^ (row & 7);
    ldsOff[j] = p * 16;
    gA[j] = A + (long)(m0 + row) * lda + ksl * 16;
    gB[j] = B + (long)(n0 + row) * ldb + ksl * 16;
  }

  f32x4 acc[4][4];
#pragma unroll
  for (int i = 0; i < 4; ++i)
#pragma unroll
    for (int j = 0; j < 4; ++j) acc[i][j] = f32x4{0.f, 0.f, 0.f, 0.f};

  const int q = lane >> 4;
  const int r16 = lane & 15;
  const int lsq = q >> 1;          // seg-half within 32B
  const int off8 = (q & 1) * 8;

  for (int kt = 0; kt < K; kt += 128) {
#pragma unroll
    for (int j = 0; j < 4; ++j) {
      async_copy16(gA[j] + kt, &lds_a[ldsOff[j]]);
      async_copy16(gB[j] + kt, &lds_b[ldsOff[j]]);
    }
    __syncthreads();
#pragma unroll
    for (int s = 0; s < 4; ++s) {    // K=32 per step
      i64 af[4], bfr[4];
#pragma unroll
      for (int i = 0; i < 4; ++i) {
        int ra = wm + i * 16 + r16;
        int pa = ((s * 2 + lsq) ^ (ra & 7)) * 16 + off8;
        af[i] = *(const i64*)&lds_a[ra * 128 + pa];
        int rb = wn + i * 16 + r16;
        int pb = ((s * 2 + lsq) ^ (rb & 7)) * 16 + off8;
        bfr[i] = *(const i64*)&lds_b[rb * 128 + pb];
      }
#pragma unroll
      for (int i = 0; i < 4; ++i)
#pragma unroll
        for (int j = 0; j < 4; ++j)
          acc[i][j] = __builtin_amdgcn_mfma_f32_16x16x32_fp8_fp8(af[i], bfr[j], acc[i][j], 0, 0, 0);
    }
    __syncthreads();
  }

  if (MODE == 0) {   // QK: exp + fp8 store + fp32 partial rowsums
    float rowsum[4][4];
#pragma unroll
    for (int i = 0; i < 4; ++i)
#pragma unroll
      for (int r = 0; r < 4; ++r) rowsum[i][r] = 0.f;
#pragma unroll
    for (int i = 0; i < 4; ++i) {
      const int row0 = m0 + wm + i * 16 + q * 4;
#pragma unroll
      for (int j = 0; j < 4; ++j) {
        const int colg = n0 + wn + j * 16 + r16;
#pragma unroll
        for (int r = 0; r < 4; ++r) {
          float pv = __expf(acc[i][j][r] * scale);
          C8[(long)(row0 + r) * ldc + colg] = to_fp8(pv);
          rowsum[i][r] += pv;
        }
      }
    }
#pragma unroll
    for (int m = 1; m <= 8; m <<= 1)
#pragma unroll
      for (int i = 0; i < 4; ++i)
#pragma unroll
        for (int r = 0; r < 4; ++r)
          rowsum[i][r] += __shfl_xor(rowsum[i][r], m, 64);
    float* lsum = (float*)lds_a;   // safe: loop-end barrier drained all reads
    if (r16 == 0) {
#pragma unroll
      for (int i = 0; i < 4; ++i)
#pragma unroll
        for (int r = 0; r < 4; ++r)
          lsum[(wm + i * 16 + q * 4 + r) * 2 + (wid & 1)] = rowsum[i][r];
    }
    __syncthreads();
    if (tid < 128) {
      float s = lsum[tid * 2] + lsum[tid * 2 + 1];
      partial[((long)blockIdx.z * gridDim.x + blockIdx.x) * 2048 + m0 + tid] = s;
    }
  } else {           // PV: normalize by rowsum (16 partial blocks, broadcast reads)
#pragma unroll
    for (int i = 0; i < 4; ++i) {
      const int row0 = m0 + wm + i * 16 + q * 4;
      float w[4];
#pragma unroll
      for (int r = 0; r < 4; ++r) {
        const float* pp = partial + (long)blockIdx.z * 16 * 2048 + row0 + r;
        float s = 0.f;
#pragma unroll
        for (int b = 0; b < 16; ++b) s += pp[b * 2048];
        w[r] = 1.f / s;
      }
#pragma unroll
      for (int j = 0; j < 4; ++j) {
        const int colg = n0 + wn + j * 16 + r16;
#pragma unroll
        for (int r = 0; r < 4; ++r)
          Cb[(long)(row0 + r) * ldc + colg] = (bf16_t)(acc[i][j][r] * w[r]);
      }
    }
  }
}

// out[row*1024+col] = sum_s part[s][row][col] + bias[col] + resid[row*512+col]
__global__ __launch_bounds__(256) void reduce_splitk(
    const float* __restrict__ part, const float* __restrict__ bias,
    const float* __restrict__ resid, float* __restrict__ out, int splits) {
  int i = blockIdx.x * 256 + threadIdx.x;
  int row = i >> 7;
  int col = (i & 127) * 4;
  float4 a = *(const float4*)(resid + (long)row * 512 + col);
  float4 b = *(const float4*)(bias + col);
  a.x += b.x; a.y += b.y; a.z += b.z; a.w += b.w;
  for (int s = 0; s < splits; ++s) {
    float4 p = *(const float4*)(part + (long)s * 2048 * 512 + (long)row * 512 + col);
    a.x += p.x; a.y += p.y; a.z += p.z; a.w += p.w;
  }
  *(float4*)(out + (long)row * 1024 + col) = a;
}

extern "C" void kernel_launch(void* const* d_in, const int* in_sizes, int n_in,
                              void* d_out, int out_size, void* d_ws, size_t ws_size,
                              hipStream_t stream)
{
  (void)in_sizes; (void)n_in; (void)out_size; (void)ws_size;
  const int N = 2048, D = 512, HD = 4096;
  const int NW = HD * D;
  const int splits = 8, Ks = HD / splits;

  const float* img_f  = (const float*)d_in[0];
  const float* meta_f = (const float*)d_in[1];
  float* out = (float*)d_out;

  // scratch: 92 MB total (ws >= 151 MB established in R3/R5)
  char* p = (char*)d_ws;
  bf16_t* imgb  = (bf16_t*)p; p += (size_t)N * D * 2;
  bf16_t* metab = (bf16_t*)p; p += (size_t)N * D * 2;
  bf16_t* wqkv  = (bf16_t*)p; p += (size_t)3 * NW * 2;   // 12 MB, reused per dir
  bf16_t* wl    = (bf16_t*)p; p += (size_t)NW * 2;       // 4 MB
  u8*     q8    = (u8*)p;     p += (size_t)N * HD;       // 8 MB fp8
  u8*     k8    = (u8*)p;     p += (size_t)N * HD;
  u8*     vt8   = (u8*)p;     p += (size_t)N * HD;       // [8][512][2048] V^T
  bf16_t* res   = (bf16_t*)p; p += (size_t)N * HD * 2;   // 16 MB bf16
  u8*     S8    = (u8*)p;     p += (size_t)8 * N * N;    // 32 MB fp8 scores
  // partial rowsums alias wqkv (consumed by proj before QK writes partials)
  float* partial = (float*)wqkv;                         // [8][16][2048] f32
  // split-K f32 partials alias S8 (PV's S reads precede splitK in stream order)
  float* spart = (float*)S8;                             // 16 MB

  const float rs = 1.f / sqrtf((float)D);
  dim3 blk(256);

  cast_f32_bf16_4<<<dim3(N * D / 1024, 2), blk, 0, stream>>>(
      img_f, meta_f, nullptr, nullptr, imgb, metab, nullptr, nullptr, N * D);

  for (int dir = 0; dir < 2; ++dir) {
    const bf16_t* Xq    = dir ? imgb  : metab;
    const bf16_t* Xkv   = dir ? metab : imgb;
    const float*  resid = dir ? meta_f : img_f;
    const float* Wq_f = (const float*)d_in[dir ? 8  : 2];
    const float* bq_f = (const float*)d_in[dir ? 9  : 3];
    const float* Wk_f = (const float*)d_in[dir ? 10 : 4];
    const float* bk_f = (const float*)d_in[dir ? 11 : 5];
    const float* Wv_f = (const float*)d_in[dir ? 12 : 6];
    const float* bv_f = (const float*)d_in[dir ? 13 : 7];
    const float* Wl_f = (const float*)d_in[dir ? 16 : 14];
    const float* bl_f = (const float*)d_in[dir ? 17 : 15];

    cast_f32_bf16_4<<<dim3(NW / 1024, 4), blk, 0, stream>>>(
        Wq_f, Wk_f, Wv_f, Wl_f, wqkv, wqkv + NW, wqkv + 2 * (size_t)NW, wl, NW);

    // merged projections: [Xq|Xkv] @ [Wq;Wk;Wv]^T -> q8 / k8 / vt8 (fp8)
    gemm_bt<4><<<dim3(96, 16, 1), blk, 0, stream>>>(
        Xq, D, 0, wqkv, D, 0, q8, HD, 0, k8, vt8,
        bq_f, bk_f, bv_f, Xkv, 1.f, D);

    // S8 = fp8(exp(Q K^T / sqrt(512))) + fp32 partial rowsums
    gemm_f8<0><<<dim3(16, 16, 8), blk, 0, stream>>>(
        q8, HD, D, k8, HD, D, S8, N, (long)N * N, partial, rs, D);

    // res = (S8 @ V) / rowsum
    gemm_f8<1><<<dim3(4, 16, 8), blk, 0, stream>>>(
        S8, N, (long)N * N, vt8 + (size_t)0, N, (long)D * N,
        res, HD, D, partial, 1.f, N);

    // output linear, split-K (bf16 x bf16 -> f32 partials)
    gemm_bt<3><<<dim3(4, 16, splits), blk, 0, stream>>>(
        res, HD, Ks, wl, HD, Ks, spart, 512, (long)N * 512,
        nullptr, nullptr, nullptr, nullptr, nullptr, nullptr, 1.f, Ks);
    reduce_splitk<<<dim3(1024), blk, 0, stream>>>(
        spart, bl_f, resid, out + dir * D, splits);
  }
}

// Round 7
// 360.732 us; speedup vs baseline: 1.6654x; 1.1665x over previous
//
#include <hip/hip_runtime.h>
#include <math.h>

typedef __bf16 bf16_t;
typedef unsigned char u8;
typedef long i64;
typedef __attribute__((ext_vector_type(8))) __bf16 bf16x8;
typedef __attribute__((ext_vector_type(4))) __bf16 bf16x4;
typedef __attribute__((ext_vector_type(4))) float f32x4;

#define AS_GLOBAL __attribute__((address_space(1)))
#define AS_LDS    __attribute__((address_space(3)))

__device__ __forceinline__ void async_copy16(const void* g, void* l) {
  __builtin_amdgcn_global_load_lds((const AS_GLOBAL void*)g, (AS_LDS void*)l, 16, 0, 0);
}

__device__ __forceinline__ u8 to_fp8(float v) {
  return (u8)(__builtin_amdgcn_cvt_pk_fp8_f32(v, v, 0, false) & 0xff);
}

struct CastArgs {
  const float* s[8];
  u8* d[8];
  int n[8];
};

// fp32 -> fp8 cast, 8 elems/thread; blockIdx.y selects tensor.
__global__ __launch_bounds__(256) void cast_f32_fp8_8(CastArgs a) {
  const int y = blockIdx.y;
  const float* s = a.s[y];
  u8* d = a.d[y];
  const int n = a.n[y];
  int i = (blockIdx.x * 256 + threadIdx.x) * 8;
  if (i >= n) return;
  float4 v0 = *(const float4*)(s + i);
  float4 v1 = *(const float4*)(s + i + 4);
  int w0 = __builtin_amdgcn_cvt_pk_fp8_f32(v0.x, v0.y, 0, false);
  w0 = __builtin_amdgcn_cvt_pk_fp8_f32(v0.z, v0.w, w0, true);
  int w1 = __builtin_amdgcn_cvt_pk_fp8_f32(v1.x, v1.y, 0, false);
  w1 = __builtin_amdgcn_cvt_pk_fp8_f32(v1.z, v1.w, w1, true);
  int2 o; o.x = w0; o.y = w1;
  *(int2*)(d + i) = o;
}

// 2-way fp32->bf16 cast (output-linear weights stay bf16 for precision).
__global__ __launch_bounds__(256) void cast_f32_bf16_2(
    const float* __restrict__ s0, const float* __restrict__ s1,
    bf16_t* __restrict__ d0, bf16_t* __restrict__ d1, int n) {
  const float* s = blockIdx.y ? s1 : s0;
  bf16_t* d = blockIdx.y ? d1 : d0;
  int i = (blockIdx.x * 256 + threadIdx.x) * 4;
  if (i >= n) return;
  float4 v = *(const float4*)(s + i);
  bf16x4 o;
  o[0] = (bf16_t)v.x; o[1] = (bf16_t)v.y; o[2] = (bf16_t)v.z; o[3] = (bf16_t)v.w;
  *(bf16x4*)(d + i) = o;
}

// ---------------- fp8 GEMM: C = A[M x K] @ B[N x K]^T, both dirs batched ----
// 128x128 tile, BK=128, mfma 16x16x32 fp8, global_load_lds(16B) + XOR swizzle.
// z-decode: MODE 2: dir=z, head=0.  MODE 0/1: dir=z>>3, head=z&7.
// MODE 0 (QK):  S8 = fp8(exp(acc*scale)); fp32 rowsums -> partial[z][bx][2048]
// MODE 1 (PV):  bf16 C = acc / (sum_{b<16} partial[z][b][row])
// MODE 2 (proj): A-switch at n0 (Xq for cols<4096, Xkv beyond); fp8 outputs:
//   cols [0,4096):     q8 [dir][row][c]          = fp8(acc + bq[c])
//   cols [4096,8192):  K8 [dir][row][c-4096]     = fp8(acc + bk[..])
//   cols [8192,12288): V8 [dir][(c-8192)][row]   = fp8(acc + bv[..])  (V^T)
template <int MODE>
__global__ __launch_bounds__(256, 2) void gemm_f8(
    const u8* __restrict__ A, const u8* __restrict__ A2, int lda, long aDir, long aHead,
    const u8* __restrict__ B, int ldb, long bDir, long bHead,
    void* __restrict__ Cv, int ldc, long cDir, long cHead,
    u8* __restrict__ K8, u8* __restrict__ V8,
    float* __restrict__ partial,
    const float* __restrict__ bq0, const float* __restrict__ bk0, const float* __restrict__ bv0,
    const float* __restrict__ bq1, const float* __restrict__ bk1, const float* __restrict__ bv1,
    float scale, int K)
{
  __shared__ __align__(16) u8 lds_a[128 * 128];
  __shared__ __align__(16) u8 lds_b[128 * 128];

  const int tid = threadIdx.x;
  const int lane = tid & 63;
  const int wid = tid >> 6;
  const int wm = (wid >> 1) * 64;
  const int wn = (wid & 1) * 64;
  const int m0 = blockIdx.y * 128;
  const int n0 = blockIdx.x * 128;
  const int z = blockIdx.z;
  const int dir = (MODE == 2) ? z : (z >> 3);
  const int head = (MODE == 2) ? 0 : (z & 7);

  const u8* Ap;
  if (MODE == 2) {
    const u8* Aq  = dir ? A : A2;    // A=img8, A2=meta8; dir0 queries=metadata
    const u8* Akv = dir ? A2 : A;
    Ap = (n0 < 4096) ? Aq : Akv;
  } else {
    Ap = A + (long)dir * aDir + (long)head * aHead;
  }
  const u8* Bp = B + (long)dir * bDir + (long)head * bHead;
  const long cOff = (long)dir * cDir + (long)head * cHead;
  u8*     C8 = (u8*)Cv + cOff;
  bf16_t* Cb = (bf16_t*)Cv + cOff;

  // 1024 16B segments per 128x128B tile; 4/thread; XOR swizzle phys=ks^(row&7)
  const u8* gA[4];
  const u8* gB[4];
  int ldsOff[4];
#pragma unroll
  for (int j = 0; j < 4; ++j) {
    int p = j * 256 + tid;
    int row = p >> 3;
    int ksl = (p & 7) ^ (row & 7);
    ldsOff[j] = p * 16;
    gA[j] = Ap + (long)(m0 + row) * lda + ksl * 16;
    gB[j] = Bp + (long)(n0 + row) * ldb + ksl * 16;
  }

  f32x4 acc[4][4];
#pragma unroll
  for (int i = 0; i < 4; ++i)
#pragma unroll
    for (int j = 0; j < 4; ++j) acc[i][j] = f32x4{0.f, 0.f, 0.f, 0.f};

  const int q = lane >> 4;
  const int r16 = lane & 15;
  const int lsq = q >> 1;
  const int off8 = (q & 1) * 8;

  for (int kt = 0; kt < K; kt += 128) {
#pragma unroll
    for (int j = 0; j < 4; ++j) {
      async_copy16(gA[j] + kt, &lds_a[ldsOff[j]]);
      async_copy16(gB[j] + kt, &lds_b[ldsOff[j]]);
    }
    __syncthreads();
#pragma unroll
    for (int s = 0; s < 4; ++s) {    // K=32 per step
      i64 af[4], bfr[4];
#pragma unroll
      for (int i = 0; i < 4; ++i) {
        int ra = wm + i * 16 + r16;
        int pa = ((s * 2 + lsq) ^ (ra & 7)) * 16 + off8;
        af[i] = *(const i64*)&lds_a[ra * 128 + pa];
        int rb = wn + i * 16 + r16;
        int pb = ((s * 2 + lsq) ^ (rb & 7)) * 16 + off8;
        bfr[i] = *(const i64*)&lds_b[rb * 128 + pb];
      }
#pragma unroll
      for (int i = 0; i < 4; ++i)
#pragma unroll
        for (int j = 0; j < 4; ++j)
          acc[i][j] = __builtin_amdgcn_mfma_f32_16x16x32_fp8_fp8(af[i], bfr[j], acc[i][j], 0, 0, 0);
    }
    __syncthreads();
  }

  // C/D layout: col=lane&15, row=(lane>>4)*4+reg  [m89-verified]
  if (MODE == 0) {   // QK
    float rowsum[4][4];
#pragma unroll
    for (int i = 0; i < 4; ++i)
#pragma unroll
      for (int r = 0; r < 4; ++r) rowsum[i][r] = 0.f;
#pragma unroll
    for (int i = 0; i < 4; ++i) {
      const int row0 = m0 + wm + i * 16 + q * 4;
#pragma unroll
      for (int j = 0; j < 4; ++j) {
        const int colg = n0 + wn + j * 16 + r16;
#pragma unroll
        for (int r = 0; r < 4; ++r) {
          float pv = __expf(acc[i][j][r] * scale);
          C8[(long)(row0 + r) * ldc + colg] = to_fp8(pv);
          rowsum[i][r] += pv;
        }
      }
    }
#pragma unroll
    for (int m = 1; m <= 8; m <<= 1)
#pragma unroll
      for (int i = 0; i < 4; ++i)
#pragma unroll
        for (int r = 0; r < 4; ++r)
          rowsum[i][r] += __shfl_xor(rowsum[i][r], m, 64);
    float* lsum = (float*)lds_a;   // safe: loop-end barrier drained all reads
    if (r16 == 0) {
#pragma unroll
      for (int i = 0; i < 4; ++i)
#pragma unroll
        for (int r = 0; r < 4; ++r)
          lsum[(wm + i * 16 + q * 4 + r) * 2 + (wid & 1)] = rowsum[i][r];
    }
    __syncthreads();
    if (tid < 128) {
      float s = lsum[tid * 2] + lsum[tid * 2 + 1];
      partial[((long)z * gridDim.x + blockIdx.x) * 2048 + m0 + tid] = s;
    }
  } else if (MODE == 1) {   // PV: normalize by rowsum
#pragma unroll
    for (int i = 0; i < 4; ++i) {
      const int row0 = m0 + wm + i * 16 + q * 4;
      float w[4];
#pragma unroll
      for (int r = 0; r < 4; ++r) {
        const float* pp = partial + (long)z * 16 * 2048 + row0 + r;
        float s = 0.f;
#pragma unroll
        for (int b = 0; b < 16; ++b) s += pp[b * 2048];
        w[r] = 1.f / s;
      }
#pragma unroll
      for (int j = 0; j < 4; ++j) {
        const int colg = n0 + wn + j * 16 + r16;
#pragma unroll
        for (int r = 0; r < 4; ++r)
          Cb[(long)(row0 + r) * ldc + colg] = (bf16_t)(acc[i][j][r] * w[r]);
      }
    }
  } else {   // MODE 2: projection epilogue
    const float* bq = dir ? bq1 : bq0;
    const float* bk = dir ? bk1 : bk0;
    const float* bv = dir ? bv1 : bv0;
    u8* k8p = K8 + (long)dir * 2048 * 4096;
    u8* v8p = V8 + (long)dir * 8 * 512 * 2048;
#pragma unroll
    for (int i = 0; i < 4; ++i) {
      const int row0 = m0 + wm + i * 16 + q * 4;
#pragma unroll
      for (int j = 0; j < 4; ++j) {
        const int colg = n0 + wn + j * 16 + r16;
        if (n0 < 4096) {
          float bvv = bq[colg];
#pragma unroll
          for (int r = 0; r < 4; ++r)
            C8[(long)(row0 + r) * 4096 + colg] = to_fp8(acc[i][j][r] + bvv);
        } else if (n0 < 8192) {
          int kc = colg - 4096;
          float bvv = bk[kc];
#pragma unroll
          for (int r = 0; r < 4; ++r)
            k8p[(long)(row0 + r) * 4096 + kc] = to_fp8(acc[i][j][r] + bvv);
        } else {
          int vcol = colg - 8192;
          float bvv = bv[vcol];
          int w = __builtin_amdgcn_cvt_pk_fp8_f32(acc[i][j][0] + bvv, acc[i][j][1] + bvv, 0, false);
          w = __builtin_amdgcn_cvt_pk_fp8_f32(acc[i][j][2] + bvv, acc[i][j][3] + bvv, w, true);
          *(int*)(v8p + (long)vcol * 2048 + row0) = w;   // 4 rows of V^T col
        }
      }
    }
  }
}

// ---------------- bf16 split-K output linear, both dirs batched -------------
// z: dir=z>>3, sp=z&7. C[z] (f32) = res[dir][:, sp*Ks:] @ wl[dir][:, sp*Ks:]^T
__global__ __launch_bounds__(256, 2) void gemm_splitk(
    const bf16_t* __restrict__ A, int lda, long aDir,
    const bf16_t* __restrict__ B, int ldb, long bDir,
    float* __restrict__ C, int ldc, long zC, int Ks)
{
  __shared__ __align__(16) bf16_t lds_a[128 * 64];
  __shared__ __align__(16) bf16_t lds_b[128 * 64];

  const int tid = threadIdx.x;
  const int lane = tid & 63;
  const int wid = tid >> 6;
  const int wm = (wid >> 1) * 64;
  const int wn = (wid & 1) * 64;
  const int m0 = blockIdx.y * 128;
  const int n0 = blockIdx.x * 128;
  const int z = blockIdx.z;
  const int dir = z >> 3, sp = z & 7;
  A += (long)dir * aDir + (long)sp * Ks;
  B += (long)dir * bDir + (long)sp * Ks;
  C += (long)z * zC;

  const bf16_t* gA[4];
  const bf16_t* gB[4];
  int ldsOff[4];
#pragma unroll
  for (int j = 0; j < 4; ++j) {
    int p = j * 256 + tid;
    int row = p >> 3;
    int ksl = (p & 7) ^ (row & 7);
    ldsOff[j] = p * 8;
    gA[j] = A + (long)(m0 + row) * lda + ksl * 8;
    gB[j] = B + (long)(n0 + row) * ldb + ksl * 8;
  }

  f32x4 acc[4][4];
#pragma unroll
  for (int i = 0; i < 4; ++i)
#pragma unroll
    for (int j = 0; j < 4; ++j) acc[i][j] = f32x4{0.f, 0.f, 0.f, 0.f};

  const int q = lane >> 4;
  const int r16 = lane & 15;

  for (int kt = 0; kt < Ks; kt += 64) {
#pragma unroll
    for (int j = 0; j < 4; ++j) {
      async_copy16(gA[j] + kt, &lds_a[ldsOff[j]]);
      async_copy16(gB[j] + kt, &lds_b[ldsOff[j]]);
    }
    __syncthreads();
#pragma unroll
    for (int s = 0; s < 2; ++s) {
      bf16x8 af[4], bfr[4];
#pragma unroll
      for (int i = 0; i < 4; ++i) {
        int ra = wm + i * 16 + r16;
        int ka = ((s * 4 + q) ^ (ra & 7)) * 8;
        af[i] = *(const bf16x8*)&lds_a[ra * 64 + ka];
        int rb = wn + i * 16 + r16;
        int kb = ((s * 4 + q) ^ (rb & 7)) * 8;
        bfr[i] = *(const bf16x8*)&lds_b[rb * 64 + kb];
      }
#pragma unroll
      for (int i = 0; i < 4; ++i)
#pragma unroll
        for (int j = 0; j < 4; ++j)
          acc[i][j] = __builtin_amdgcn_mfma_f32_16x16x32_bf16(af[i], bfr[j], acc[i][j], 0, 0, 0);
    }
    __syncthreads();
  }

#pragma unroll
  for (int i = 0; i < 4; ++i) {
    const int row0 = m0 + wm + i * 16 + q * 4;
#pragma unroll
    for (int j = 0; j < 4; ++j) {
      const int colg = n0 + wn + j * 16 + r16;
#pragma unroll
      for (int r = 0; r < 4; ++r)
        C[(long)(row0 + r) * ldc + colg] = acc[i][j][r];
    }
  }
}

// out[row][dir*512+col] = sum_s spart[dir][s][row][col] + bias[col] + resid[row][col]
__global__ __launch_bounds__(256) void reduce_splitk(
    const float* __restrict__ spart,
    const float* __restrict__ b0, const float* __restrict__ b1,
    const float* __restrict__ r0, const float* __restrict__ r1,
    float* __restrict__ out) {
  const int dir = blockIdx.y;
  const float* part = spart + (long)dir * 8 * 2048 * 512;
  const float* bias = dir ? b1 : b0;
  const float* resid = dir ? r1 : r0;
  int i = blockIdx.x * 256 + threadIdx.x;
  int row = i >> 7;
  int col = (i & 127) * 4;
  float4 a = *(const float4*)(resid + (long)row * 512 + col);
  float4 b = *(const float4*)(bias + col);
  a.x += b.x; a.y += b.y; a.z += b.z; a.w += b.w;
  for (int s = 0; s < 8; ++s) {
    float4 p = *(const float4*)(part + (long)s * 2048 * 512 + (long)row * 512 + col);
    a.x += p.x; a.y += p.y; a.z += p.z; a.w += p.w;
  }
  *(float4*)(out + (long)row * 1024 + dir * 512 + col) = a;
}

extern "C" void kernel_launch(void* const* d_in, const int* in_sizes, int n_in,
                              void* d_out, int out_size, void* d_ws, size_t ws_size,
                              hipStream_t stream)
{
  (void)in_sizes; (void)n_in; (void)out_size; (void)ws_size;
  const int N = 2048, D = 512, HD = 4096;
  const int NW = HD * D;                       // 2,097,152

  const float* img_f  = (const float*)d_in[0];
  const float* meta_f = (const float*)d_in[1];
  float* out = (float*)d_out;

  // scratch: 168 MB (ws ~= 268 MB per R6 fill counter)
  char* pp = (char*)d_ws;
  u8*     img8  = (u8*)pp;     pp += (size_t)N * D;            // 1 MB
  u8*     meta8 = (u8*)pp;     pp += (size_t)N * D;
  u8*     w8    = (u8*)pp;     pp += (size_t)2 * 3 * NW;       // 12 MB [dir][q,k,v]
  bf16_t* wl16  = (bf16_t*)pp; pp += 0; pp += (size_t)2 * NW * 2;  // 8 MB
  u8*     q8    = (u8*)pp;     pp += (size_t)2 * N * HD;       // 16 MB
  u8*     k8    = (u8*)pp;     pp += (size_t)2 * N * HD;       // 16 MB
  u8*     vt8   = (u8*)pp;     pp += (size_t)2 * N * HD;       // 16 MB [dir][8][512][2048]
  bf16_t* res   = (bf16_t*)pp; pp += (size_t)2 * N * HD * 2;   // 32 MB
  u8*     S8    = (u8*)pp;     pp += (size_t)2 * 8 * N * N;    // 64 MB [dir][8][N][N]
  float*  partial = (float*)pp; pp += (size_t)2 * 8 * 16 * 2048 * 4;  // 2 MB
  float*  spart = (float*)S8;  // 64 MB f32 == S8 size; safe: PV reads S8 before splitK writes

  const float rs = 1.f / sqrtf((float)D);
  dim3 blk(256);

  // cast X + the 6 QKV weights to fp8 (dir0: Wq_m,Wk_i,Wv_i; dir1: Wq_i,Wk_m,Wv_m)
  CastArgs ca;
  ca.s[0] = img_f;                    ca.d[0] = img8;          ca.n[0] = N * D;
  ca.s[1] = meta_f;                   ca.d[1] = meta8;         ca.n[1] = N * D;
  ca.s[2] = (const float*)d_in[2];    ca.d[2] = w8;            ca.n[2] = NW;
  ca.s[3] = (const float*)d_in[4];    ca.d[3] = w8 + (size_t)NW;     ca.n[3] = NW;
  ca.s[4] = (const float*)d_in[6];    ca.d[4] = w8 + (size_t)2 * NW; ca.n[4] = NW;
  ca.s[5] = (const float*)d_in[8];    ca.d[5] = w8 + (size_t)3 * NW; ca.n[5] = NW;
  ca.s[6] = (const float*)d_in[10];   ca.d[6] = w8 + (size_t)4 * NW; ca.n[6] = NW;
  ca.s[7] = (const float*)d_in[12];   ca.d[7] = w8 + (size_t)5 * NW; ca.n[7] = NW;
  cast_f32_fp8_8<<<dim3(NW / 2048, 8), blk, 0, stream>>>(ca);

  // output-linear weights -> bf16
  cast_f32_bf16_2<<<dim3(NW / 1024, 2), blk, 0, stream>>>(
      (const float*)d_in[14], (const float*)d_in[16], wl16, wl16 + NW, NW);

  // merged projections, both dirs: [Xq|Xkv] @ [Wq;Wk;Wv]^T -> q8/k8/vt8
  gemm_f8<2><<<dim3(96, 16, 2), blk, 0, stream>>>(
      img8, meta8, D, 0, 0,
      w8, D, (long)3 * NW, 0,
      q8, HD, (long)N * HD, 0,
      k8, vt8, nullptr,
      (const float*)d_in[3], (const float*)d_in[5], (const float*)d_in[7],
      (const float*)d_in[9], (const float*)d_in[11], (const float*)d_in[13],
      1.f, D);

  // QK, both dirs x 8 heads: S8 = fp8(exp(QK^T/sqrt(512))) + rowsum partials
  gemm_f8<0><<<dim3(16, 16, 16), blk, 0, stream>>>(
      q8, nullptr, HD, (long)N * HD, D,
      k8, HD, (long)N * HD, D,
      S8, N, (long)8 * N * N, (long)N * N,
      nullptr, nullptr, partial,
      nullptr, nullptr, nullptr, nullptr, nullptr, nullptr,
      rs, D);

  // PV: res = (S8 @ V) / rowsum
  gemm_f8<1><<<dim3(4, 16, 16), blk, 0, stream>>>(
      S8, nullptr, N, (long)8 * N * N, (long)N * N,
      vt8, N, (long)8 * D * N, (long)D * N,
      res, HD, (long)N * HD, D,
      nullptr, nullptr, partial,
      nullptr, nullptr, nullptr, nullptr, nullptr, nullptr,
      1.f, N);

  // output linear, split-K, both dirs (bf16 -> f32 partials in spart)
  gemm_splitk<<<dim3(4, 16, 16), blk, 0, stream>>>(
      res, HD, (long)N * HD,
      wl16, HD, (long)NW,
      spart, D, (long)N * D, D);

  reduce_splitk<<<dim3(1024, 2), blk, 0, stream>>>(
      spart, (const float*)d_in[15], (const float*)d_in[17],
      img_f, meta_f, out);
}